// Round 6
// baseline (1057.383 us; speedup 1.0000x reference)
//
#include <hip/hip_runtime.h>

#define H_DIM 2048
#define KEY_DIM 2048
#define VAL_DIM 4096
#define CONV_DIM 8192
#define QKVZ_DIM 12288
#define NS_ELEMS 524288
#define NC_ELEMS 24576
#define NPQ 16
#define NBLK 512

typedef float f32x4 __attribute__((ext_vector_type(4)));

__device__ __forceinline__ float silu_f(float x) { return x / (1.f + expf(-x)); }
__device__ __forceinline__ f32x4 ntload4(const float* p) {
  return __builtin_nontemporal_load(reinterpret_cast<const f32x4*>(p));
}
__device__ __forceinline__ void ntstore4(float* p, f32x4 v) {
  __builtin_nontemporal_store(v, reinterpret_cast<f32x4*>(p));
}

struct KParams {
  const float* hidden;
  const float* Wq;
  const float* Wba;
  const float* cw;
  const float* dtb;
  const float* Al;
  const float* nw;
  const float* Wo;
  const float* S[4];
  const float* C[4];
  float* out;
  unsigned* barcnt;   // [1]
  unsigned* bargen;   // [1]
  unsigned* headcnt;  // [4*32]
  float* qpart;       // NPQ * QKVZ_DIM
  float* bapart;      // NPQ * 64
  float* o2part;      // 32*16
  float* o_raw;       // 4096
  float* zfin;        // 4096
  float* ypart;       // 32 * H_DIM
};

__device__ __forceinline__ void gbar(unsigned* cnt, unsigned* gen, int t) {
  __syncthreads();
  if (t == 0) {
    unsigned g = __hip_atomic_load(gen, __ATOMIC_RELAXED, __HIP_MEMORY_SCOPE_AGENT);
    unsigned a = __hip_atomic_fetch_add(cnt, 1u, __ATOMIC_ACQ_REL, __HIP_MEMORY_SCOPE_AGENT);
    if (a == NBLK - 1) {
      __hip_atomic_store(cnt, 0u, __ATOMIC_RELAXED, __HIP_MEMORY_SCOPE_AGENT);
      __hip_atomic_store(gen, g + 1u, __ATOMIC_RELEASE, __HIP_MEMORY_SCOPE_AGENT);
    } else {
      while (__hip_atomic_load(gen, __ATOMIC_RELAXED, __HIP_MEMORY_SCOPE_AGENT) == g)
        __builtin_amdgcn_s_sleep(2);
      (void)__hip_atomic_load(gen, __ATOMIC_ACQUIRE, __HIP_MEMORY_SCOPE_AGENT);
    }
  }
  __syncthreads();
}

__global__ __launch_bounds__(256, 4) void fused_all(KParams P)
{
  const int bid = blockIdx.x, t = threadIdx.x;
  __shared__ float hs[128];
  __shared__ f32x4 red[256];
  __shared__ float kk[128], qq[128], vv[8], of[128], sc[8], o2s[8];

  for (int L = 0; L < 4; ++L) {
    const float* Wq   = P.Wq  + (size_t)L * H_DIM * QKVZ_DIM;
    const float* Wba  = P.Wba + (size_t)L * H_DIM * 64;
    const float* Wo   = P.Wo  + (size_t)L * VAL_DIM * H_DIM;
    const float* cw   = P.cw  + (size_t)L * CONV_DIM * 4;
    const float* S_in = P.S[L];
    const float* C_in = P.C[L];
    float* nS = P.out + 2048 + (size_t)L * (NS_ELEMS + NC_ELEMS);
    float* nC = nS + NS_ELEMS;

    // ================= STAGE A: qkvz/ba partial GEMVs =================
    for (int tt = 0; tt < 3; ++tt) {
      int tau = bid + tt * NBLK;          // 0..1535
      int p = tau / 96, cc = tau % 96;
      int rb = p * 128;
      __syncthreads();
      if (t < 128) {
        float s = 0.f;
        if (L == 0) {
          s = P.hidden[rb + t];
        } else {
#pragma unroll
          for (int h2 = 0; h2 < 32; ++h2) s += P.ypart[h2 * H_DIM + rb + t];
        }
        hs[t] = s;
      }
      __syncthreads();
      int rg = t >> 5, cg = t & 31;
      const float* wp = Wq + (size_t)(rb + rg * 16) * QKVZ_DIM + cc * 128 + cg * 4;
      f32x4 acc = {0.f, 0.f, 0.f, 0.f};
#pragma unroll
      for (int ii = 0; ii < 16; ++ii)
        acc += hs[rg * 16 + ii] * ntload4(wp + (size_t)ii * QKVZ_DIM);
      red[t] = acc;
      __syncthreads();
      if (t < 32) {
        f32x4 o = red[t] + red[t + 32] + red[t + 64] + red[t + 96] +
                  red[t + 128] + red[t + 160] + red[t + 192] + red[t + 224];
        *reinterpret_cast<f32x4*>(P.qpart + (size_t)p * QKVZ_DIM + cc * 128 + t * 4) = o;
      }
    }
    if (bid < 16) {   // ba tiles
      int rb = bid * 128;
      __syncthreads();
      if (t < 128) {
        float s = 0.f;
        if (L == 0) {
          s = P.hidden[rb + t];
        } else {
#pragma unroll
          for (int h2 = 0; h2 < 32; ++h2) s += P.ypart[h2 * H_DIM + rb + t];
        }
        hs[t] = s;
      }
      __syncthreads();
      int col = t & 63, rg = t >> 6;
      float a = 0.f;
#pragma unroll
      for (int ii = 0; ii < 32; ++ii)
        a += hs[rg * 32 + ii] * Wba[(size_t)(rb + rg * 32 + ii) * 64 + col];
      red[t].x = a;
      __syncthreads();
      if (t < 64)
        P.bapart[bid * 64 + t] = red[t].x + red[t + 64].x + red[t + 128].x + red[t + 192].x;
    }
    gbar(P.barcnt, P.bargen, t);

    // ================= STAGE B: conv+state+norm+out-GEMV =================
    {
      int hh = bid >> 4, sub = bid & 15;
      int r0 = sub * 8;
      int kqh = hh >> 1;
      auto convval = [&](int c, float last) -> float {
        f32x4 w = *reinterpret_cast<const f32x4*>(cw + (size_t)c * 4);
        float val = C_in[c] * w.x + C_in[CONV_DIM + c] * w.y +
                    C_in[2 * CONV_DIM + c] * w.z + last * w.w;
        return silu_f(val);
      };
      // phase 1: k,q reduce + conv
      if (t < 128) {
        int c = KEY_DIM + kqh * 128 + t;
        float s = 0.f;
#pragma unroll
        for (int p = 0; p < NPQ; ++p) s += P.qpart[(size_t)p * QKVZ_DIM + c];
        kk[t] = convval(c, s);
      } else {
        int u = t - 128;
        int c = kqh * 128 + u;
        float s = 0.f;
#pragma unroll
        for (int p = 0; p < NPQ; ++p) s += P.qpart[(size_t)p * QKVZ_DIM + c];
        qq[u] = convval(c, s);
      }
      __syncthreads();
      // phase 2: norms, v, z, scalars
      if (t < 64) {
        float v = kk[t] * kk[t] + kk[t + 64] * kk[t + 64];
        for (int m = 32; m; m >>= 1) v += __shfl_xor(v, m, 64);
        if (t == 0) sc[0] = v;
      } else if (t < 128) {
        int u = t - 64;
        float v = qq[u] * qq[u] + qq[u + 64] * qq[u + 64];
        for (int m = 32; m; m >>= 1) v += __shfl_xor(v, m, 64);
        if (u == 0) sc[1] = v;
      } else if (t < 136) {
        int j = t - 128;
        int c = 2 * KEY_DIM + hh * 128 + r0 + j;
        float s = 0.f;
#pragma unroll
        for (int p = 0; p < NPQ; ++p) s += P.qpart[(size_t)p * QKVZ_DIM + c];
        vv[j] = convval(c, s);
      } else if (t < 144) {
        int j = t - 136;
        int c = CONV_DIM + hh * 128 + r0 + j;
        float s = 0.f;
#pragma unroll
        for (int p = 0; p < NPQ; ++p) s += P.qpart[(size_t)p * QKVZ_DIM + c];
        P.zfin[hh * 128 + r0 + j] = s;
      } else if (t == 144) {
        float bs = 0.f, as = 0.f;
#pragma unroll
        for (int p = 0; p < NPQ; ++p) {
          bs += P.bapart[p * 64 + hh];
          as += P.bapart[p * 64 + 32 + hh];
        }
        float x = as + P.dtb[L * 32 + hh];
        float sp = (x > 15.f) ? x : log1pf(expf(x));
        sc[2] = 1.f / (1.f + expf(-bs));
        sc[3] = expf(-expf(P.Al[L * 32 + hh]) * sp);
      }
      __syncthreads();
      // phase 3: state update for 8 rows
      {
        float rk = rsqrtf(sc[0] + 1e-6f), rq = rsqrtf(sc[1] + 1e-6f);
        float beta = sc[2], decay = sc[3];
        int j = t >> 5, lane = t & 31;
        int d0 = lane * 4;
        f32x4 k4 = {kk[d0] * rk, kk[d0 + 1] * rk, kk[d0 + 2] * rk, kk[d0 + 3] * rk};
        f32x4 q4 = {qq[d0] * rq, qq[d0 + 1] * rq, qq[d0 + 2] * rq, qq[d0 + 3] * rq};
        size_t idx = ((size_t)(hh * 128 + r0 + j)) * 128 + d0;
        f32x4 s = *reinterpret_cast<const f32x4*>(S_in + idx);
        s *= decay;
        float kv = s.x * k4.x + s.y * k4.y + s.z * k4.z + s.w * k4.w;
        for (int m = 16; m; m >>= 1) kv += __shfl_xor(kv, m, 32);
        float dl = (vv[j] - kv) * beta;
        f32x4 s1 = s + dl * k4;
        ntstore4(nS + idx, s1);
        float op = s1.x * q4.x + s1.y * q4.y + s1.z * q4.z + s1.w * q4.w;
        for (int m = 16; m; m >>= 1) op += __shfl_xor(op, m, 32);
        if (lane == 0) {
          float o = op * 0.088388347648318447f;  // DK^-0.5
          P.o_raw[hh * 128 + r0 + j] = o;
          o2s[j] = o * o;
        }
      }
      __syncthreads();
      if (t == 0) {
        float s = 0.f;
#pragma unroll
        for (int j = 0; j < 8; ++j) s += o2s[j];
        P.o2part[hh * 16 + sub] = s;
        // intra-head latch: arrive (release) then wait for all 16 sub-blocks
        unsigned* hc = P.headcnt + L * 32 + hh;
        __hip_atomic_fetch_add(hc, 1u, __ATOMIC_RELEASE, __HIP_MEMORY_SCOPE_AGENT);
        while (__hip_atomic_load(hc, __ATOMIC_RELAXED, __HIP_MEMORY_SCOPE_AGENT) < 16u)
          __builtin_amdgcn_s_sleep(1);
        (void)__hip_atomic_load(hc, __ATOMIC_ACQUIRE, __HIP_MEMORY_SCOPE_AGENT);
      }
      __syncthreads();
      // phase 4: normalize + gate
      if (t < 128) {
        float o2 = 0.f;
#pragma unroll
        for (int s2 = 0; s2 < 16; ++s2) o2 += P.o2part[hh * 16 + s2];
        float rs = rsqrtf(o2 * (1.f / 128.f) + 1e-6f);
        of[t] = P.o_raw[hh * 128 + t] * rs * P.nw[L * 128 + t] * silu_f(P.zfin[hh * 128 + t]);
      }
      __syncthreads();
      // phase 5: out-GEMV slice (cols sub*128..+128, rows = head)
      {
        int rg = t >> 5, cg = t & 31;
        const float* wp = Wo + (size_t)(hh * 128 + rg * 16) * H_DIM + sub * 128 + cg * 4;
        f32x4 acc = {0.f, 0.f, 0.f, 0.f};
#pragma unroll
        for (int ii = 0; ii < 16; ++ii)
          acc += of[rg * 16 + ii] * ntload4(wp + (size_t)ii * H_DIM);
        red[t] = acc;
        __syncthreads();
        if (t < 32) {
          f32x4 o = red[t] + red[t + 32] + red[t + 64] + red[t + 96] +
                    red[t + 128] + red[t + 160] + red[t + 192] + red[t + 224];
          *reinterpret_cast<f32x4*>(P.ypart + (size_t)hh * H_DIM + sub * 128 + t * 4) = o;
        }
      }
      // nC chores: 12 float4 per block
      if (t < 12) {
        int idx4 = bid * 12 + t;          // 0..6143
        int c4 = idx4 * 4;
        int row = c4 >> 13;
        int cc2 = c4 & (CONV_DIM - 1);
        f32x4 v;
        if (row < 2) {
          v = *reinterpret_cast<const f32x4*>(C_in + (row + 1) * CONV_DIM + cc2);
        } else {
          v = (f32x4){0.f, 0.f, 0.f, 0.f};
#pragma unroll
          for (int p = 0; p < NPQ; ++p)
            v += *reinterpret_cast<const f32x4*>(P.qpart + (size_t)p * QKVZ_DIM + cc2);
        }
        ntstore4(nC + row * CONV_DIM + cc2, v);
      }
    }
    gbar(P.barcnt, P.bargen, t);
  }

  // final: reduce y partials -> out[0:2048]
  if (bid < 8) {
    int c = bid * 256 + t;
    float s = 0.f;
#pragma unroll
    for (int h2 = 0; h2 < 32; ++h2) s += P.ypart[h2 * H_DIM + c];
    P.out[c] = s;
  }
}

extern "C" void kernel_launch(void* const* d_in, const int* in_sizes, int n_in,
                              void* d_out, int out_size, void* d_ws, size_t ws_size,
                              hipStream_t stream)
{
  KParams P;
  P.hidden = (const float*)d_in[0];
  for (int L = 0; L < 4; ++L) {
    P.S[L] = (const float*)d_in[1 + 2 * L];
    P.C[L] = (const float*)d_in[2 + 2 * L];
  }
  P.Wq  = (const float*)d_in[9];
  P.Wba = (const float*)d_in[10];
  P.cw  = (const float*)d_in[11];
  P.dtb = (const float*)d_in[12];
  P.Al  = (const float*)d_in[13];
  P.nw  = (const float*)d_in[14];
  P.Wo  = (const float*)d_in[15];
  P.out = (float*)d_out;

  // ws layout: control region (zeroed each call) then float buffers
  unsigned* ctl = (unsigned*)d_ws;
  P.barcnt  = ctl;            // 1
  P.bargen  = ctl + 1;        // 1
  P.headcnt = ctl + 2;        // 128
  float* f = (float*)d_ws + 512;          // 2KB control region
  P.qpart  = f;               f += NPQ * QKVZ_DIM;   // 196608
  P.bapart = f;               f += NPQ * 64;         // 1024
  P.o2part = f;               f += 32 * 16;          // 512
  P.o_raw  = f;               f += 4096;
  P.zfin   = f;               f += 4096;
  P.ypart  = f;               f += 32 * H_DIM;       // 65536

  hipMemsetAsync(d_ws, 0, 2048, stream);
  fused_all<<<NBLK, 256, 0, stream>>>(P);
}

// Round 8
// 545.113 us; speedup vs baseline: 1.9398x; 1.9398x over previous
//
#include <hip/hip_runtime.h>

#define H_DIM 2048
#define KEY_DIM 2048
#define CONV_DIM 8192
#define QKVZ_DIM 12288
#define NS_ELEMS 524288
#define NC_ELEMS 24576
#define NPQ 16
#define NBLK 768

typedef float f32x4 __attribute__((ext_vector_type(4)));

__device__ __forceinline__ float silu_f(float x) { return x / (1.f + expf(-x)); }
__device__ __forceinline__ f32x4 ld4(const float* p) {
  return *reinterpret_cast<const f32x4*>(p);
}
__device__ __forceinline__ void ntst4(float* p, f32x4 v) {
  __builtin_nontemporal_store(v, reinterpret_cast<f32x4*>(p));
}
// Coherent (sc0/sc1) scalar access for cross-block ws data: relaxed system-scope
// atomics lower to plain load/store with cache-bypass bits, NO flush instructions.
__device__ __forceinline__ float atldf(const float* p) {
  return __hip_atomic_load(p, __ATOMIC_RELAXED, __HIP_MEMORY_SCOPE_SYSTEM);
}
__device__ __forceinline__ void atstf(float* p, float v) {
  __hip_atomic_store(p, v, __ATOMIC_RELAXED, __HIP_MEMORY_SCOPE_SYSTEM);
}
#define ATLD(p) __hip_atomic_load((p), __ATOMIC_RELAXED, __HIP_MEMORY_SCOPE_SYSTEM)
#define ATST(p, v) __hip_atomic_store((p), (v), __ATOMIC_RELAXED, __HIP_MEMORY_SCOPE_SYSTEM)
#define ATADD(p, v) __hip_atomic_fetch_add((p), (v), __ATOMIC_RELAXED, __HIP_MEMORY_SCOPE_SYSTEM)

struct KParams {
  const float* hidden;
  const float* Wq;
  const float* Wba;
  const float* cw;
  const float* dtb;
  const float* Al;
  const float* nw;
  const float* Wo;
  const float* S[4];
  const float* C[4];
  float* out;
  unsigned* ctl;    // [4096]: cnt 16x64, gen@1024, ggen 12x64@1088, headcnt 128x16@2048
  float* qpart;     // NPQ * QKVZ_DIM
  float* bapart;    // 64 * 64
  float* o2part;    // 32 * 16
  float* o_raw;     // 4096
  float* zfin;      // 4096
  float* ypart;     // 32 * H_DIM
};

// Flush-free two-level grid barrier: RELAXED atomics only.
__device__ __forceinline__ void gbar(unsigned* ctl, unsigned phase, int bid, int t) {
  asm volatile("s_waitcnt vmcnt(0)" ::: "memory");
  __syncthreads();
  if (t == 0) {
    ATADD(&ctl[(bid & 15) * 64], 1u);
    int g = bid >> 6;
    if (bid == 0) {
      for (;;) {
        unsigned s = 0;
#pragma unroll
        for (int i = 0; i < 16; ++i) s += ATLD(&ctl[i * 64]);
        if (s >= (unsigned)NBLK * phase) break;
        __builtin_amdgcn_s_sleep(2);
      }
      ATST(&ctl[1024], phase);
    }
    if ((bid & 63) == 0) {
      while (ATLD(&ctl[1024]) < phase) __builtin_amdgcn_s_sleep(4);
      ATST(&ctl[1088 + g * 64], phase);
    } else {
      while (ATLD(&ctl[1088 + g * 64]) < phase) __builtin_amdgcn_s_sleep(8);
    }
  }
  __syncthreads();
}

__global__ __launch_bounds__(256, 3) void fused_all(KParams P)
{
  const int bid = blockIdx.x, t = threadIdx.x;
  __shared__ float hs[128];
  __shared__ f32x4 red[256];
  __shared__ float kk[128], qq[128], vv[8], of[128], sc[8], o2s[8];

  for (int L = 0; L < 4; ++L) {
    const float* Wq   = P.Wq  + (size_t)L * H_DIM * QKVZ_DIM;
    const float* Wba  = P.Wba + (size_t)L * H_DIM * 64;
    const float* Wo   = P.Wo  + (size_t)L * 4096 * H_DIM;
    const float* cw   = P.cw  + (size_t)L * CONV_DIM * 4;
    const float* S_in = P.S[L];
    const float* C_in = P.C[L];
    float* nS = P.out + 2048 + (size_t)L * (NS_ELEMS + NC_ELEMS);
    float* nC = nS + NS_ELEMS;

    // ================= STAGE A: qkvz/ba partial GEMVs =================
    {
      int p = (2 * bid) / 96, cc0 = (2 * bid) % 96;
      if (t < 128) {
        float s = 0.f;
        if (L == 0) {
          s = P.hidden[p * 128 + t];
        } else {
#pragma unroll
          for (int h2 = 0; h2 < 32; ++h2) s += atldf(&P.ypart[h2 * H_DIM + p * 128 + t]);
        }
        hs[t] = s;
      }
      __syncthreads();
      int rg = t >> 5, cg = t & 31;
#pragma unroll
      for (int tile = 0; tile < 2; ++tile) {
        int cc = cc0 + tile;
        const float* wp = Wq + (size_t)(p * 128 + rg * 16) * QKVZ_DIM + cc * 128 + cg * 4;
        f32x4 acc = {0.f, 0.f, 0.f, 0.f};
#pragma unroll
        for (int ii = 0; ii < 16; ++ii)
          acc += hs[rg * 16 + ii] * ld4(wp + (size_t)ii * QKVZ_DIM);
        red[t] = acc;
        __syncthreads();
        if (t < 32) {
          f32x4 o = red[t] + red[t + 32] + red[t + 64] + red[t + 96] +
                    red[t + 128] + red[t + 160] + red[t + 192] + red[t + 224];
          float* qp = P.qpart + (size_t)p * QKVZ_DIM + cc * 128 + t * 4;
          atstf(qp + 0, o.x); atstf(qp + 1, o.y);
          atstf(qp + 2, o.z); atstf(qp + 3, o.w);
        }
        __syncthreads();
      }
      if (bid % 12 == 0) {  // ba victim: 64 tiles of 32 rows x 64 cols
        int r = bid / 12;                  // 0..63 ; hs rows cover this tile
        int col = t & 63, rowg = t >> 6;
        float a = 0.f;
#pragma unroll
        for (int ii = 0; ii < 8; ++ii) {
          int lr = 32 * (r & 3) + rowg * 8 + ii;
          a += hs[lr] * Wba[(size_t)(32 * r + rowg * 8 + ii) * 64 + col];
        }
        red[t].x = a;
        __syncthreads();
        if (t < 64)
          atstf(&P.bapart[r * 64 + t],
                red[t].x + red[t + 64].x + red[t + 128].x + red[t + 192].x);
      }
    }
    gbar(P.ctl, (unsigned)(2 * L + 1), bid, t);

    // ================= STAGE B =================
    if (bid < 512) {
      int hh = bid >> 4, sub = bid & 15;
      int r0 = sub * 8;
      int kqh = hh >> 1;
      auto convval = [&](int c, float last) -> float {
        f32x4 w = ld4(cw + (size_t)c * 4);
        float val = C_in[c] * w.x + C_in[CONV_DIM + c] * w.y +
                    C_in[2 * CONV_DIM + c] * w.z + last * w.w;
        return silu_f(val);
      };
      // phase 1: k,q reduce + conv
      if (t < 128) {
        int c = KEY_DIM + kqh * 128 + t;
        float s = 0.f;
#pragma unroll
        for (int p = 0; p < NPQ; ++p) s += atldf(&P.qpart[(size_t)p * QKVZ_DIM + c]);
        kk[t] = convval(c, s);
      } else {
        int u = t - 128;
        int c = kqh * 128 + u;
        float s = 0.f;
#pragma unroll
        for (int p = 0; p < NPQ; ++p) s += atldf(&P.qpart[(size_t)p * QKVZ_DIM + c]);
        qq[u] = convval(c, s);
      }
      __syncthreads();
      // phase 2: norms, v, z, scalars
      if (t < 64) {
        float v = kk[t] * kk[t] + kk[t + 64] * kk[t + 64];
        for (int m = 32; m; m >>= 1) v += __shfl_xor(v, m, 64);
        if (t == 0) sc[0] = v;
      } else if (t < 128) {
        int u = t - 64;
        float v = qq[u] * qq[u] + qq[u + 64] * qq[u + 64];
        for (int m = 32; m; m >>= 1) v += __shfl_xor(v, m, 64);
        if (u == 0) sc[1] = v;
      } else if (t < 136) {
        int j = t - 128;
        int c = 2 * KEY_DIM + hh * 128 + r0 + j;
        float s = 0.f;
#pragma unroll
        for (int p = 0; p < NPQ; ++p) s += atldf(&P.qpart[(size_t)p * QKVZ_DIM + c]);
        vv[j] = convval(c, s);
      } else if (t < 144) {
        int j = t - 136;
        int c = CONV_DIM + hh * 128 + r0 + j;
        float s = 0.f;
#pragma unroll
        for (int p = 0; p < NPQ; ++p) s += atldf(&P.qpart[(size_t)p * QKVZ_DIM + c]);
        atstf(&P.zfin[hh * 128 + r0 + j], s);
      } else if (t == 144) {
        float bs = 0.f;
#pragma unroll
        for (int p = 0; p < 64; ++p) bs += atldf(&P.bapart[p * 64 + hh]);
        sc[2] = 1.f / (1.f + expf(-bs));
      } else if (t == 145) {
        float as = 0.f;
#pragma unroll
        for (int p = 0; p < 64; ++p) as += atldf(&P.bapart[p * 64 + 32 + hh]);
        float x = as + P.dtb[L * 32 + hh];
        float sp = (x > 15.f) ? x : log1pf(expf(x));
        sc[3] = expf(-expf(P.Al[L * 32 + hh]) * sp);
      }
      __syncthreads();
      // phase 3: state update for this sub-block's 8 rows
      {
        float rk = rsqrtf(sc[0] + 1e-6f), rq = rsqrtf(sc[1] + 1e-6f);
        float beta = sc[2], decay = sc[3];
        int j = t >> 5, lane = t & 31;
        int d0 = lane * 4;
        f32x4 k4 = {kk[d0] * rk, kk[d0 + 1] * rk, kk[d0 + 2] * rk, kk[d0 + 3] * rk};
        f32x4 q4 = {qq[d0] * rq, qq[d0 + 1] * rq, qq[d0 + 2] * rq, qq[d0 + 3] * rq};
        size_t idx = ((size_t)(hh * 128 + r0 + j)) * 128 + d0;
        f32x4 s = ld4(S_in + idx);
        s *= decay;
        float kv = s.x * k4.x + s.y * k4.y + s.z * k4.z + s.w * k4.w;
        for (int m = 16; m; m >>= 1) kv += __shfl_xor(kv, m, 32);
        float dl = (vv[j] - kv) * beta;
        f32x4 s1 = s + dl * k4;
        ntst4(nS + idx, s1);
        float op = s1.x * q4.x + s1.y * q4.y + s1.z * q4.z + s1.w * q4.w;
        for (int m = 16; m; m >>= 1) op += __shfl_xor(op, m, 32);
        if (lane == 0) {
          float o = op * 0.088388347648318447f;  // DK^-0.5
          atstf(&P.o_raw[hh * 128 + r0 + j], o);
          o2s[j] = o * o;
        }
      }
      __syncthreads();
      if (t == 0) {
        float s2 = 0.f;
#pragma unroll
        for (int j = 0; j < 8; ++j) s2 += o2s[j];
        atstf(&P.o2part[hh * 16 + sub], s2);
      }
      // intra-head latch (relaxed-only, per-head cache line)
      asm volatile("s_waitcnt vmcnt(0)" ::: "memory");
      __syncthreads();
      if (t == 0) {
        unsigned* hc = &P.ctl[2048 + (L * 32 + hh) * 16];
        ATADD(hc, 1u);
        while (ATLD(hc) < 16u) __builtin_amdgcn_s_sleep(2);
      }
      __syncthreads();
      // phase 4: normalize + gate
      if (t < 128) {
        float o2 = 0.f;
#pragma unroll
        for (int s2 = 0; s2 < 16; ++s2) o2 += atldf(&P.o2part[hh * 16 + s2]);
        float rs = rsqrtf(o2 * (1.f / 128.f) + 1e-6f);
        of[t] = atldf(&P.o_raw[hh * 128 + t]) * rs * P.nw[L * 128 + t] *
                silu_f(atldf(&P.zfin[hh * 128 + t]));
      }
      __syncthreads();
      // phase 5: out-GEMV slice (head rows, cols sub*128..+127)
      {
        int rg = t >> 5, cg = t & 31;
        const float* wp = Wo + (size_t)(hh * 128 + rg * 16) * H_DIM + sub * 128 + cg * 4;
        f32x4 acc = {0.f, 0.f, 0.f, 0.f};
#pragma unroll
        for (int ii = 0; ii < 16; ++ii)
          acc += of[rg * 16 + ii] * ld4(wp + (size_t)ii * H_DIM);
        red[t] = acc;
        __syncthreads();
        if (t < 32) {
          f32x4 o = red[t] + red[t + 32] + red[t + 64] + red[t + 96] +
                    red[t + 128] + red[t + 160] + red[t + 192] + red[t + 224];
          float* yp = P.ypart + (size_t)hh * H_DIM + sub * 128 + t * 4;
          atstf(yp + 0, o.x); atstf(yp + 1, o.y);
          atstf(yp + 2, o.z); atstf(yp + 3, o.w);
        }
      }
      // nC chores: 12 float4 per block
      if (t < 12) {
        int idx4 = bid * 12 + t;  // 0..6143
        int c4 = idx4 * 4;
        int row = c4 >> 13;
        int cc2 = c4 & (CONV_DIM - 1);
        f32x4 v;
        if (row < 2) {
          v = ld4(C_in + (row + 1) * CONV_DIM + cc2);
        } else {
          v = (f32x4){0.f, 0.f, 0.f, 0.f};
#pragma unroll
          for (int p = 0; p < NPQ; ++p) {
            const float* qp = P.qpart + (size_t)p * QKVZ_DIM + cc2;
            v.x += atldf(qp + 0); v.y += atldf(qp + 1);
            v.z += atldf(qp + 2); v.w += atldf(qp + 3);
          }
        }
        ntst4(nC + row * CONV_DIM + cc2, v);
      }
    } else if (L < 3) {
      // prefetch blocks: warm caches with part of next layer's Wq
      int j = bid - 512;
      const float* Wn = P.Wq + (size_t)(L + 1) * H_DIM * QKVZ_DIM;
#pragma unroll
      for (int i = 0; i < 6; ++i) {
        float v = Wn[((size_t)(j * 6 + i) * 256 + t) * 32];
        asm volatile("" :: "v"(v));
      }
    }
    gbar(P.ctl, (unsigned)(2 * L + 2), bid, t);
  }

  // final: reduce y partials -> out[0:2048]
  if (bid < 8) {
    int c = bid * 256 + t;
    float s = 0.f;
#pragma unroll
    for (int h2 = 0; h2 < 32; ++h2) s += atldf(&P.ypart[h2 * H_DIM + c]);
    P.out[c] = s;
  }
}

extern "C" void kernel_launch(void* const* d_in, const int* in_sizes, int n_in,
                              void* d_out, int out_size, void* d_ws, size_t ws_size,
                              hipStream_t stream)
{
  KParams P;
  P.hidden = (const float*)d_in[0];
  for (int L = 0; L < 4; ++L) {
    P.S[L] = (const float*)d_in[1 + 2 * L];
    P.C[L] = (const float*)d_in[2 + 2 * L];
  }
  P.Wq  = (const float*)d_in[9];
  P.Wba = (const float*)d_in[10];
  P.cw  = (const float*)d_in[11];
  P.dtb = (const float*)d_in[12];
  P.Al  = (const float*)d_in[13];
  P.nw  = (const float*)d_in[14];
  P.Wo  = (const float*)d_in[15];
  P.out = (float*)d_out;

  P.ctl = (unsigned*)d_ws;                 // 4096 uints = 16KB, zeroed per call
  float* f = (float*)d_ws + 4096;
  P.qpart  = f;  f += NPQ * QKVZ_DIM;      // 196608
  P.bapart = f;  f += 64 * 64;             // 4096
  P.o2part = f;  f += 32 * 16;             // 512
  P.o_raw  = f;  f += 4096;
  P.zfin   = f;  f += 4096;
  P.ypart  = f;  f += 32 * H_DIM;          // 65536

  hipMemsetAsync(d_ws, 0, 16384, stream);
  fused_all<<<NBLK, 256, 0, stream>>>(P);
}

// Round 9
// 427.026 us; speedup vs baseline: 2.4762x; 1.2765x over previous
//
#include <hip/hip_runtime.h>

#define H_DIM 2048
#define KEY_DIM 2048
#define CONV_DIM 8192
#define QKVZ_DIM 12288
#define NS_ELEMS 524288
#define NC_ELEMS 24576
#define NPQ 16
#define NBLK 768

typedef float f32x4 __attribute__((ext_vector_type(4)));

__device__ __forceinline__ float silu_f(float x) { return x / (1.f + expf(-x)); }
__device__ __forceinline__ f32x4 ld4(const float* p) {
  return *reinterpret_cast<const f32x4*>(p);
}
__device__ __forceinline__ void st4(float* p, f32x4 v) {
  *reinterpret_cast<f32x4*>(p) = v;
}
// Coherent (sc0/sc1) access: relaxed system-scope atomics — no cache flushes.
__device__ __forceinline__ float atldf(const float* p) {
  return __hip_atomic_load(p, __ATOMIC_RELAXED, __HIP_MEMORY_SCOPE_SYSTEM);
}
__device__ __forceinline__ void atstf(float* p, float v) {
  __hip_atomic_store(p, v, __ATOMIC_RELAXED, __HIP_MEMORY_SCOPE_SYSTEM);
}
union U64F2 { unsigned long long u; float f[2]; };
__device__ __forceinline__ void atld2(const float* p, float& a, float& b) {
  U64F2 x;
  x.u = __hip_atomic_load((const unsigned long long*)p, __ATOMIC_RELAXED, __HIP_MEMORY_SCOPE_SYSTEM);
  a = x.f[0]; b = x.f[1];
}
__device__ __forceinline__ void atst2(float* p, float a, float b) {
  U64F2 x; x.f[0] = a; x.f[1] = b;
  __hip_atomic_store((unsigned long long*)p, x.u, __ATOMIC_RELAXED, __HIP_MEMORY_SCOPE_SYSTEM);
}
#define ATLD(p) __hip_atomic_load((p), __ATOMIC_RELAXED, __HIP_MEMORY_SCOPE_SYSTEM)
#define ATST(p, v) __hip_atomic_store((p), (v), __ATOMIC_RELAXED, __HIP_MEMORY_SCOPE_SYSTEM)
#define ATADD(p, v) __hip_atomic_fetch_add((p), (v), __ATOMIC_RELAXED, __HIP_MEMORY_SCOPE_SYSTEM)

struct KParams {
  const float* hidden;
  const float* Wq;
  const float* Wba;
  const float* cw;
  const float* dtb;
  const float* Al;
  const float* nw;
  const float* Wo;
  const float* S[4];
  const float* C[4];
  float* out;
  unsigned* ctl;
  float* qpart;   // NPQ * QKVZ_DIM
  float* qfin;    // QKVZ_DIM
  float* bapart;  // 64 * 64
  float* o2part;  // 32 * 16
  float* o_raw;   // 4096
  float* ypart;   // 32 * H_DIM
  float* yfin;    // H_DIM
};

// ctl layout (uints): [0..1023] barrier cnt 16x64; [1024] gen; [1088+g*64] relay (12);
// [2048 + (L*48+chunk)*16] chunk latches; [8192 + (L*32+hh)*16] head latches;
// [16384 + L*16] ycnt.
__device__ __forceinline__ void gbar(unsigned* ctl, unsigned phase, int bid, int t) {
  asm volatile("s_waitcnt vmcnt(0)" ::: "memory");
  __syncthreads();
  if (t == 0) {
    ATADD(&ctl[(bid & 15) * 64], 1u);
    int g = bid >> 6;
    if (bid == 0) {
      for (;;) {
        unsigned s = 0;
#pragma unroll
        for (int i = 0; i < 16; ++i) s += ATLD(&ctl[i * 64]);
        if (s >= (unsigned)NBLK * phase) break;
        __builtin_amdgcn_s_sleep(2);
      }
      ATST(&ctl[1024], phase);
    }
    if ((bid & 63) == 0) {
      while (ATLD(&ctl[1024]) < phase) __builtin_amdgcn_s_sleep(4);
      ATST(&ctl[1088 + g * 64], phase);
    } else {
      while (ATLD(&ctl[1088 + g * 64]) < phase) __builtin_amdgcn_s_sleep(8);
    }
  }
  __syncthreads();
}

__global__ __launch_bounds__(256, 3) void fused_all(KParams P)
{
  const int bid = blockIdx.x, t = threadIdx.x;
  __shared__ float hs[128];
  __shared__ f32x4 red[256];
  __shared__ float kk[128], qq[128], vv[8], of[128], sc[8], o2s[8];

  for (int L = 0; L < 4; ++L) {
    const float* Wq   = P.Wq  + (size_t)L * H_DIM * QKVZ_DIM;
    const float* Wba  = P.Wba + (size_t)L * H_DIM * 64;
    const float* Wo   = P.Wo  + (size_t)L * 4096 * H_DIM;
    const float* cw   = P.cw  + (size_t)L * CONV_DIM * 4;
    const float* S_in = P.S[L];
    const float* C_in = P.C[L];
    float* nS = P.out + 2048 + (size_t)L * (NS_ELEMS + NC_ELEMS);
    float* nC = nS + NS_ELEMS;

    // ================= STAGE A =================
    {
      int p = bid / 48, chunk = bid % 48;
      if (L == 0) {
        if (t < 128) hs[t] = P.hidden[p * 128 + t];
      } else {
        if (t < 64) atld2(P.yfin + p * 128 + t * 2, hs[t * 2], hs[t * 2 + 1]);
      }
      __syncthreads();
      int rg = t >> 5, cg = t & 31;
#pragma unroll
      for (int tile = 0; tile < 2; ++tile) {
        int colbase = chunk * 256 + tile * 128;
        const float* wp = Wq + (size_t)(p * 128 + rg * 16) * QKVZ_DIM + colbase + cg * 4;
        f32x4 acc = {0.f, 0.f, 0.f, 0.f};
#pragma unroll
        for (int ii = 0; ii < 16; ++ii)
          acc += hs[rg * 16 + ii] * ld4(wp + (size_t)ii * QKVZ_DIM);
        red[t] = acc;
        __syncthreads();
        if (t < 32) {
          f32x4 o = red[t] + red[t + 32] + red[t + 64] + red[t + 96] +
                    red[t + 128] + red[t + 160] + red[t + 192] + red[t + 224];
          float* qp = P.qpart + (size_t)p * QKVZ_DIM + colbase + t * 4;
          atst2(qp, o.x, o.y);
          atst2(qp + 2, o.z, o.w);
        }
        __syncthreads();
      }
      // ba tiles: blocks with chunk<4 handle rows r=p*4+chunk (32 rows x 64 cols)
      {
        float a = 0.f;
        int r = p * 4 + chunk;
        if (chunk < 4) {
          int col = t & 63, rowg = t >> 6;
#pragma unroll
          for (int ii = 0; ii < 8; ++ii)
            a += hs[32 * chunk + rowg * 8 + ii] * Wba[(size_t)(32 * r + rowg * 8 + ii) * 64 + col];
        }
        red[t].x = a;
        __syncthreads();
        if (chunk < 4 && t < 64)
          atstf(&P.bapart[r * 64 + t],
                red[t].x + red[t + 64].x + red[t + 128].x + red[t + 192].x);
      }
      // chunk latch; p==0 block reduces its 256 cols into qfin
      asm volatile("s_waitcnt vmcnt(0)" ::: "memory");
      __syncthreads();
      if (t == 0) {
        unsigned* cl = &P.ctl[2048 + (L * 48 + chunk) * 16];
        ATADD(cl, 1u);
        if (p == 0)
          while (ATLD(cl) < 16u) __builtin_amdgcn_s_sleep(2);
      }
      __syncthreads();
      if (p == 0) {
        int c = chunk * 256 + t;
        float s = 0.f;
#pragma unroll
        for (int pp = 0; pp < NPQ; ++pp) s += atldf(&P.qpart[(size_t)pp * QKVZ_DIM + c]);
        atstf(&P.qfin[c], s);
      }
    }
    gbar(P.ctl, (unsigned)(2 * L + 1), bid, t);

    // ================= STAGE B =================
    if (bid < 512) {
      int hh = bid >> 4, sub = bid & 15;
      int r0 = sub * 8;
      int kqh = hh >> 1;
      auto convval = [&](int c, float last) -> float {
        f32x4 w = ld4(cw + (size_t)c * 4);
        float val = C_in[c] * w.x + C_in[CONV_DIM + c] * w.y +
                    C_in[2 * CONV_DIM + c] * w.z + last * w.w;
        return silu_f(val);
      };
      // phase 1: k,q conv from qfin
      if (t < 128) {
        int c = KEY_DIM + kqh * 128 + t;
        kk[t] = convval(c, atldf(&P.qfin[c]));
      } else {
        int u = t - 128;
        int c = kqh * 128 + u;
        qq[u] = convval(c, atldf(&P.qfin[c]));
      }
      __syncthreads();
      // phase 2: norms, v, ba scalars
      if (t < 64) {
        float v = kk[t] * kk[t] + kk[t + 64] * kk[t + 64];
        for (int m = 32; m; m >>= 1) v += __shfl_xor(v, m, 64);
        if (t == 0) sc[0] = v;
      } else if (t < 128) {
        int u = t - 64;
        float v = qq[u] * qq[u] + qq[u + 64] * qq[u + 64];
        for (int m = 32; m; m >>= 1) v += __shfl_xor(v, m, 64);
        if (u == 0) sc[1] = v;
      } else if (t < 136) {
        int j = t - 128;
        int c = 2 * KEY_DIM + hh * 128 + r0 + j;
        vv[j] = convval(c, atldf(&P.qfin[c]));
      } else if (t == 144) {
        float bs = 0.f;
#pragma unroll
        for (int p = 0; p < 64; ++p) bs += atldf(&P.bapart[p * 64 + hh]);
        sc[2] = 1.f / (1.f + expf(-bs));
      } else if (t == 145) {
        float as = 0.f;
#pragma unroll
        for (int p = 0; p < 64; ++p) as += atldf(&P.bapart[p * 64 + 32 + hh]);
        float x = as + P.dtb[L * 32 + hh];
        float sp = (x > 15.f) ? x : log1pf(expf(x));
        sc[3] = expf(-expf(P.Al[L * 32 + hh]) * sp);
      }
      __syncthreads();
      // phase 3: state update for this sub-block's 8 rows
      {
        float rk = rsqrtf(sc[0] + 1e-6f), rq = rsqrtf(sc[1] + 1e-6f);
        float beta = sc[2], decay = sc[3];
        int j = t >> 5, lane = t & 31;
        int d0 = lane * 4;
        f32x4 k4 = {kk[d0] * rk, kk[d0 + 1] * rk, kk[d0 + 2] * rk, kk[d0 + 3] * rk};
        f32x4 q4 = {qq[d0] * rq, qq[d0 + 1] * rq, qq[d0 + 2] * rq, qq[d0 + 3] * rq};
        size_t idx = ((size_t)(hh * 128 + r0 + j)) * 128 + d0;
        f32x4 s = ld4(S_in + idx);
        s *= decay;
        float kv = s.x * k4.x + s.y * k4.y + s.z * k4.z + s.w * k4.w;
        for (int m = 16; m; m >>= 1) kv += __shfl_xor(kv, m, 32);
        float dl = (vv[j] - kv) * beta;
        f32x4 s1 = s + dl * k4;
        st4(nS + idx, s1);
        float op = s1.x * q4.x + s1.y * q4.y + s1.z * q4.z + s1.w * q4.w;
        for (int m = 16; m; m >>= 1) op += __shfl_xor(op, m, 32);
        if (lane == 0) {
          float o = op * 0.088388347648318447f;  // DK^-0.5
          atstf(&P.o_raw[hh * 128 + r0 + j], o);
          o2s[j] = o * o;
        }
      }
      __syncthreads();
      if (t == 0) {
        float s2 = 0.f;
#pragma unroll
        for (int j = 0; j < 8; ++j) s2 += o2s[j];
        atstf(&P.o2part[hh * 16 + sub], s2);
      }
      // intra-head latch
      asm volatile("s_waitcnt vmcnt(0)" ::: "memory");
      __syncthreads();
      if (t == 0) {
        unsigned* hc = &P.ctl[8192 + (L * 32 + hh) * 16];
        ATADD(hc, 1u);
        while (ATLD(hc) < 16u) __builtin_amdgcn_s_sleep(2);
      }
      __syncthreads();
      // phase 4: normalize + gate (z read straight from qfin)
      if (t < 128) {
        float o2 = 0.f;
#pragma unroll
        for (int s2 = 0; s2 < 16; ++s2) o2 += atldf(&P.o2part[hh * 16 + s2]);
        float rs = rsqrtf(o2 * (1.f / 128.f) + 1e-6f);
        of[t] = atldf(&P.o_raw[hh * 128 + t]) * rs * P.nw[L * 128 + t] *
                silu_f(atldf(&P.qfin[CONV_DIM + hh * 128 + t]));
      }
      __syncthreads();
      // phase 5: out-GEMV slice (head rows, cols sub*128..+127)
      {
        int rg = t >> 5, cg = t & 31;
        const float* wp = Wo + (size_t)(hh * 128 + rg * 16) * H_DIM + sub * 128 + cg * 4;
        f32x4 acc = {0.f, 0.f, 0.f, 0.f};
#pragma unroll
        for (int ii = 0; ii < 16; ++ii)
          acc += of[rg * 16 + ii] * ld4(wp + (size_t)ii * H_DIM);
        red[t] = acc;
        __syncthreads();
        if (t < 32) {
          f32x4 o = red[t] + red[t + 32] + red[t + 64] + red[t + 96] +
                    red[t + 128] + red[t + 160] + red[t + 192] + red[t + 224];
          float* yp = P.ypart + (size_t)hh * H_DIM + sub * 128 + t * 4;
          atst2(yp, o.x, o.y);
          atst2(yp + 2, o.z, o.w);
        }
      }
      // nC chores: rows 0,1 from C_in; row 2 = pre-conv mixed = qfin[0:8192]
      if (t < 12) {
        int idx4 = bid * 12 + t;  // 0..6143
        int c4 = idx4 * 4;
        int row = c4 >> 13;
        int cc2 = c4 & (CONV_DIM - 1);
        f32x4 v;
        if (row < 2) {
          v = ld4(C_in + (row + 1) * CONV_DIM + cc2);
        } else {
          v.x = atldf(&P.qfin[cc2]);     v.y = atldf(&P.qfin[cc2 + 1]);
          v.z = atldf(&P.qfin[cc2 + 2]); v.w = atldf(&P.qfin[cc2 + 3]);
        }
        st4(nC + row * CONV_DIM + cc2, v);
      }
      asm volatile("s_waitcnt vmcnt(0)" ::: "memory");
      __syncthreads();
      if (t == 0) ATADD(&P.ctl[16384 + L * 16], 1u);
    } else if (bid < 520) {
      // y reducers: wait for all 512 stage-B blocks, then reduce ypart -> yfin/out
      if (t == 0)
        while (ATLD(&P.ctl[16384 + L * 16]) < 512u) __builtin_amdgcn_s_sleep(2);
      __syncthreads();
      if (t < 128) {
        int c = (bid - 512) * 256 + t * 2;
        float sa = 0.f, sb = 0.f;
#pragma unroll
        for (int h2 = 0; h2 < 32; ++h2) {
          float a, b;
          atld2(P.ypart + (size_t)h2 * H_DIM + c, a, b);
          sa += a; sb += b;
        }
        if (L < 3) atst2(P.yfin + c, sa, sb);
        else { P.out[c] = sa; P.out[c + 1] = sb; }
      }
    } else if (L < 3) {
      // prefetch next layer's Wq (one float per 64B line)
      int j = bid - 520;
      const float* Wn = P.Wq + (size_t)(L + 1) * H_DIM * QKVZ_DIM;
#pragma unroll
      for (int i = 0; i < 4; ++i) {
        float v = Wn[((size_t)(j * 4 + i) * 256 + t) * 16];
        asm volatile("" :: "v"(v));
      }
    }
    gbar(P.ctl, (unsigned)(2 * L + 2), bid, t);
  }
}

extern "C" void kernel_launch(void* const* d_in, const int* in_sizes, int n_in,
                              void* d_out, int out_size, void* d_ws, size_t ws_size,
                              hipStream_t stream)
{
  KParams P;
  P.hidden = (const float*)d_in[0];
  for (int L = 0; L < 4; ++L) {
    P.S[L] = (const float*)d_in[1 + 2 * L];
    P.C[L] = (const float*)d_in[2 + 2 * L];
  }
  P.Wq  = (const float*)d_in[9];
  P.Wba = (const float*)d_in[10];
  P.cw  = (const float*)d_in[11];
  P.dtb = (const float*)d_in[12];
  P.Al  = (const float*)d_in[13];
  P.nw  = (const float*)d_in[14];
  P.Wo  = (const float*)d_in[15];
  P.out = (float*)d_out;

  P.ctl = (unsigned*)d_ws;                 // 128 KB control region, zeroed per call
  float* f = (float*)d_ws + 32768;
  P.qpart  = f;  f += NPQ * QKVZ_DIM;      // 196608
  P.qfin   = f;  f += QKVZ_DIM;            // 12288
  P.bapart = f;  f += 64 * 64;             // 4096
  P.o2part = f;  f += 32 * 16;             // 512
  P.o_raw  = f;  f += 4096;
  P.ypart  = f;  f += 32 * H_DIM;          // 65536
  P.yfin   = f;  f += H_DIM;               // 2048

  hipMemsetAsync(d_ws, 0, 131072, stream);
  fused_all<<<NBLK, 256, 0, stream>>>(P);
}

// Round 10
// 186.353 us; speedup vs baseline: 5.6741x; 2.2915x over previous
//
#include <hip/hip_runtime.h>

#define H_DIM 2048
#define KEY_DIM 2048
#define CONV_DIM 8192
#define QKVZ_DIM 12288
#define NS_ELEMS 524288
#define NC_ELEMS 24576
#define NPQ 16

typedef float f32x4 __attribute__((ext_vector_type(4)));

__device__ __forceinline__ float silu_f(float x) { return x / (1.f + expf(-x)); }
__device__ __forceinline__ f32x4 ld4(const float* p) {
  return *reinterpret_cast<const f32x4*>(p);
}
__device__ __forceinline__ void st4(float* p, f32x4 v) {
  *reinterpret_cast<f32x4*>(p) = v;
}

// ---------------- K1: qkvz partials (16 x QKVZ_DIM) and ba partials ----------
// blocks 0..1535: 16 row-blocks x 96 col-chunks, 128x128 tile each
// blocks 1536..1551: ba, one 128-row x 64-col tile each
__global__ __launch_bounds__(256, 6) void k_qkvz(
    const float* __restrict__ hsrc, int hparts,
    const float* __restrict__ Wq, const float* __restrict__ Wba,
    float* __restrict__ qpart, float* __restrict__ bapart)
{
  int bid = blockIdx.x, t = threadIdx.x;
  __shared__ float hs[128];
  __shared__ f32x4 red[256];
  int rb = (bid < 1536) ? (bid / 96) * 128 : (bid - 1536) * 128;
  if (t < 128) {
    float s = 0.f;
    if (hparts == 1) {
      s = hsrc[rb + t];
    } else {
#pragma unroll
      for (int p = 0; p < 32; ++p) s += hsrc[p * H_DIM + rb + t];
    }
    hs[t] = s;
  }
  __syncthreads();
  if (bid < 1536) {
    int p = bid / 96, chunk = bid % 96;
    int rg = t >> 5, cg = t & 31;
    const float* wp = Wq + (size_t)(rb + rg * 16) * QKVZ_DIM + chunk * 128 + cg * 4;
    f32x4 acc = {0.f, 0.f, 0.f, 0.f};
#pragma unroll
    for (int ii = 0; ii < 16; ++ii)
      acc += hs[rg * 16 + ii] * ld4(wp + (size_t)ii * QKVZ_DIM);
    red[t] = acc;
    __syncthreads();
    if (t < 32) {
      f32x4 o = red[t] + red[t + 32] + red[t + 64] + red[t + 96] +
                red[t + 128] + red[t + 160] + red[t + 192] + red[t + 224];
      st4(qpart + (size_t)p * QKVZ_DIM + chunk * 128 + t * 4, o);
    }
  } else {
    int r = bid - 1536;
    int col = t & 63, rowg = t >> 6;
    float a = 0.f;
#pragma unroll
    for (int ii = 0; ii < 32; ++ii)
      a += hs[rowg * 32 + ii] * Wba[(size_t)(rb + rowg * 32 + ii) * 64 + col];
    red[t].x = a;
    __syncthreads();
    if (t < 64)
      bapart[r * 64 + t] = red[t].x + red[t + 64].x + red[t + 128].x + red[t + 192].x;
  }
}

// ---------------- K2: fused conv + state update + norm + out-GEMV ----------
// blocks 0..511: head hh = bid>>4, col-chunk = bid&15 (128 cols of Wo).
// Each block redundantly computes its head's full state (S slice is L2/L3-hot);
// only chunk==0 stores nS. blocks 512..535: nC.
__global__ __launch_bounds__(256, 4) void k_stateout(
    const float* __restrict__ S_in, const float* __restrict__ C_in,
    const float* __restrict__ qpart, const float* __restrict__ bapart,
    const float* __restrict__ cw, const float* __restrict__ dtb,
    const float* __restrict__ Al, const float* __restrict__ nw,
    const float* __restrict__ Wo,
    float* __restrict__ nS, float* __restrict__ nC, float* __restrict__ ypart)
{
  int bid = blockIdx.x, t = threadIdx.x;
  if (bid < 512) {
    int hh = bid >> 4, chunk = bid & 15, kqh = hh >> 1;
    __shared__ float kk[128], qq[128], vvf[128], zz[128], of[128], sc[8];
    auto red16 = [&](int c) -> float {
      float s = 0.f;
#pragma unroll
      for (int p = 0; p < NPQ; ++p) s += qpart[(size_t)p * QKVZ_DIM + c];
      return s;
    };
    auto convval = [&](int c, float last) -> float {
      f32x4 w = ld4(cw + (size_t)c * 4);
      float val = C_in[c] * w.x + C_in[CONV_DIM + c] * w.y +
                  C_in[2 * CONV_DIM + c] * w.z + last * w.w;
      return silu_f(val);
    };
    // phase A: k,q
    if (t < 128) {
      int c = KEY_DIM + kqh * 128 + t;
      kk[t] = convval(c, red16(c));
    } else {
      int u = t - 128;
      int c = kqh * 128 + u;
      qq[u] = convval(c, red16(c));
    }
    __syncthreads();
    // phase B: v, z
    if (t < 128) {
      int c = 2 * KEY_DIM + hh * 128 + t;
      vvf[t] = convval(c, red16(c));
    } else {
      int u = t - 128;
      zz[u] = red16(CONV_DIM + hh * 128 + u);
    }
    __syncthreads();
    // phase C: norms + gate scalars
    if (t < 64) {
      float v = kk[t] * kk[t] + kk[t + 64] * kk[t + 64];
      for (int m = 32; m; m >>= 1) v += __shfl_xor(v, m, 64);
      if (t == 0) sc[0] = v;
    } else if (t < 128) {
      int u = t - 64;
      float v = qq[u] * qq[u] + qq[u + 64] * qq[u + 64];
      for (int m = 32; m; m >>= 1) v += __shfl_xor(v, m, 64);
      if (u == 0) sc[1] = v;
    } else if (t == 128) {
      float bs = 0.f;
#pragma unroll
      for (int p = 0; p < NPQ; ++p) bs += bapart[p * 64 + hh];
      sc[2] = 1.f / (1.f + expf(-bs));
    } else if (t == 129) {
      float as = 0.f;
#pragma unroll
      for (int p = 0; p < NPQ; ++p) as += bapart[p * 64 + 32 + hh];
      float x = as + dtb[hh];
      float sp = (x > 15.f) ? x : log1pf(expf(x));
      sc[3] = expf(-expf(Al[hh]) * sp);
    }
    __syncthreads();
    // phase D: state update, full head (redundant per chunk; only chunk 0 stores)
    {
      float rk = rsqrtf(sc[0] + 1e-6f), rq = rsqrtf(sc[1] + 1e-6f);
      float beta = sc[2], decay = sc[3];
      int grp = t >> 5, lane = t & 31;
      int d0 = lane * 4;
      f32x4 k4 = {kk[d0] * rk, kk[d0 + 1] * rk, kk[d0 + 2] * rk, kk[d0 + 3] * rk};
      f32x4 q4 = {qq[d0] * rq, qq[d0 + 1] * rq, qq[d0 + 2] * rq, qq[d0 + 3] * rq};
#pragma unroll 4
      for (int j = 0; j < 16; ++j) {
        int row = j * 8 + grp;
        size_t idx = ((size_t)(hh * 128 + row)) * 128 + d0;
        f32x4 s = ld4(S_in + idx);
        s *= decay;
        float kv = s.x * k4.x + s.y * k4.y + s.z * k4.z + s.w * k4.w;
        for (int m = 16; m; m >>= 1) kv += __shfl_xor(kv, m, 32);
        float dl = (vvf[row] - kv) * beta;
        f32x4 s1 = s + dl * k4;
        if (chunk == 0) st4(nS + idx, s1);
        float op = s1.x * q4.x + s1.y * q4.y + s1.z * q4.z + s1.w * q4.w;
        for (int m = 16; m; m >>= 1) op += __shfl_xor(op, m, 32);
        if (lane == 0) of[row] = op * 0.088388347648318447f;  // DK^-0.5
      }
    }
    __syncthreads();
    // phase E: RMS denom
    if (t < 64) {
      float v = of[t] * of[t] + of[t + 64] * of[t + 64];
      for (int m = 32; m; m >>= 1) v += __shfl_xor(v, m, 64);
      if (t == 0) sc[4] = v;
    }
    __syncthreads();
    // phase F: normalize + gate
    if (t < 128) {
      float rs = rsqrtf(sc[4] * (1.f / 128.f) + 1e-6f);
      of[t] = of[t] * rs * nw[t] * silu_f(zz[t]);
    }
    __syncthreads();
    // phase G: out-GEMV slice (head rows x 128 cols)
    {
      __shared__ f32x4 red[256];
      int rg = t >> 5, cg = t & 31;
      const float* wp = Wo + (size_t)(hh * 128 + rg * 16) * H_DIM + chunk * 128 + cg * 4;
      f32x4 acc = {0.f, 0.f, 0.f, 0.f};
#pragma unroll
      for (int ii = 0; ii < 16; ++ii)
        acc += of[rg * 16 + ii] * ld4(wp + (size_t)ii * H_DIM);
      red[t] = acc;
      __syncthreads();
      if (t < 32) {
        f32x4 o = red[t] + red[t + 32] + red[t + 64] + red[t + 96] +
                  red[t + 128] + red[t + 160] + red[t + 192] + red[t + 224];
        st4(ypart + (size_t)hh * H_DIM + chunk * 128 + t * 4, o);
      }
    }
  } else {
    // nC: rows 0,1 <- C_in rows 1,2 ; row 2 <- reduced pre-conv mixed (qkvz[0:8192])
    int gt = (bid - 512) * 256 + t;  // float4 index
    if (gt < NC_ELEMS / 4) {
      int c4 = gt * 4;
      int row = c4 >> 13;
      int cc = c4 & (CONV_DIM - 1);
      f32x4 v;
      if (row < 2) {
        v = ld4(C_in + (row + 1) * CONV_DIM + cc);
      } else {
        v = (f32x4){0.f, 0.f, 0.f, 0.f};
#pragma unroll
        for (int p = 0; p < NPQ; ++p)
          v += ld4(qpart + (size_t)p * QKVZ_DIM + cc);
      }
      st4(nC + row * CONV_DIM + cc, v);
    }
  }
}

// ---------------- K3: reduce final y partials -> d_out[0:2048] -------------
__global__ __launch_bounds__(256) void k_final(const float* __restrict__ ypart,
                                               float* __restrict__ dst) {
  int c = blockIdx.x * 256 + threadIdx.x;
  float s = 0.f;
#pragma unroll
  for (int p = 0; p < 32; ++p) s += ypart[p * H_DIM + c];
  dst[c] = s;
}

extern "C" void kernel_launch(void* const* d_in, const int* in_sizes, int n_in,
                              void* d_out, int out_size, void* d_ws, size_t ws_size,
                              hipStream_t stream)
{
  const float* hidden  = (const float*)d_in[0];
  const float* Wq_all  = (const float*)d_in[9];
  const float* Wba_all = (const float*)d_in[10];
  const float* cw_all  = (const float*)d_in[11];
  const float* dtb_all = (const float*)d_in[12];
  const float* Al_all  = (const float*)d_in[13];
  const float* nw_all  = (const float*)d_in[14];
  const float* Wo_all  = (const float*)d_in[15];
  float* out = (float*)d_out;
  float* f   = (float*)d_ws;

  // ws layout — every buffer fully overwritten before read; no zeroing needed
  float* qpart  = f;  f += NPQ * QKVZ_DIM;   // 196608
  float* bapart = f;  f += NPQ * 64;         // 1024
  float* ypart  = f;  f += 32 * H_DIM;       // 65536

  for (int L = 0; L < 4; ++L) {
    const float* hsrc = (L == 0) ? hidden : ypart;
    int hparts        = (L == 0) ? 1 : 32;
    const float* S_in = (const float*)d_in[1 + 2 * L];
    const float* C_in = (const float*)d_in[2 + 2 * L];
    float* nS = out + 2048 + (size_t)L * (NS_ELEMS + NC_ELEMS);
    float* nC = nS + NS_ELEMS;

    k_qkvz<<<1552, 256, 0, stream>>>(
        hsrc, hparts,
        Wq_all + (size_t)L * H_DIM * QKVZ_DIM,
        Wba_all + (size_t)L * H_DIM * 64,
        qpart, bapart);

    k_stateout<<<536, 256, 0, stream>>>(
        S_in, C_in, qpart, bapart,
        cw_all + (size_t)L * CONV_DIM * 4,
        dtb_all + L * 32, Al_all + L * 32, nw_all + L * 128,
        Wo_all + (size_t)L * 4096 * H_DIM,
        nS, nC, ypart);
  }
  k_final<<<8, 256, 0, stream>>>(ypart, out);
}